// Round 8
// baseline (568.921 us; speedup 1.0000x reference)
//
#include <hip/hip_runtime.h>
#include <stdint.h>

#define KCAPS 10
#define OC    16
#define IC    256
#define HWSZ  36
#define PRIM  72
#define PD    8
#define EDIM  16

typedef short bf16x8 __attribute__((ext_vector_type(8)));
typedef float f32x4  __attribute__((ext_vector_type(4)));

// persistent prepped weights (recomputed every launch -> deterministic)
__device__ unsigned short g_whi[KCAPS * OC * IC];
__device__ unsigned short g_wlo[KCAPS * OC * IC];
__device__ float          g_wtsT[KCAPS * PRIM * EDIM * PD];   // [k][p][e][d]

// LDS map (44352 B):
//   [0, 19008)      xsh u32[36][132]  (bf16 [36][264])
//   [19008, 38016)  xsl u32[36][132]
//   [38016, 44352)  slack: GEMM A-fragment reads for discarded D-rows 36..47
//                   run past xsl (garbage, in-bounds, results discarded)
//   after GEMM barrier (xs dead):
//   [0, 23040)      caps f32[10][576]  (wave k writes/reads only capsule k slice)
//   [23040, 25920)  b_s f32[720]
//   [25920, 28800)  c_s f32[720]
#define SMEM_BYTES 44352

__device__ __forceinline__ void bf_split(float v, unsigned short& hb, unsigned short& lb) {
    __bf16 h = (__bf16)v;
    hb = __builtin_bit_cast(unsigned short, h);
    __bf16 l = (__bf16)(v - (float)h);
    lb = __builtin_bit_cast(unsigned short, l);
}

__device__ __forceinline__ f32x4 mfma16(bf16x8 a, bf16x8 b, f32x4 c) {
    return __builtin_amdgcn_mfma_f32_16x16x32_bf16(a, b, c, 0, 0, 0);
}

__global__ __launch_bounds__(256)
void prep_kernel(const float* __restrict__ w, const float* __restrict__ wts) {
    int i = blockIdx.x * 256 + threadIdx.x;
    if (i < KCAPS * OC * IC) {
        unsigned short hb, lb;
        bf_split(w[i], hb, lb);
        g_whi[i] = hb;
        g_wlo[i] = lb;
    }
    if (i < KCAPS * PRIM * EDIM * PD) {           // 92160: [kp][e][d] <- [kp][d][e]
        int d = i & 7, e = (i >> 3) & 15, kp = i >> 7;
        g_wtsT[i] = wts[(size_t)kp * 128 + d * 16 + e];
    }
}

__global__ __launch_bounds__(512, 6)
void caps_512(const float* __restrict__ x, const float* __restrict__ conv_b,
              float* __restrict__ out) {
    extern __shared__ char smem[];
    uint32_t* xsh = (uint32_t*)smem;              // [36][132]
    uint32_t* xsl = xsh + 36 * 132;               // [36][132] (+slack beyond)
    const short* xshS = (const short*)xsh;
    const short* xslS = (const short*)xsl;
    float* caps_s = (float*)smem;                 // [10][576], overlays xs post-GEMM
    float* b_s    = (float*)smem + 5760;          // [720]
    float* c_s    = b_s + 720;                    // [720]

    const int t  = threadIdx.x;
    const int bb = blockIdx.x;
    const int wv = t >> 6;            // wave 0..7; owns capsule wv (+ capsule 8+wv if wv<2)
    const int ln = t & 63;
    const int row = ln & 15;          // GEMM: tile row | routing: e
    const int g   = ln >> 4;          // GEMM: k-group  | routing: pr
    const int e   = row;
    const int pr  = g;
    const bool dual = (wv < 2);
    const int kB = 8 + wv;            // second capsule for dual waves

    // ---- phase 0: stage x transposed -> bf16 hi/lo [36 hw][264 c]
    {
        const float4* x4 = (const float4*)(x + (size_t)bb * (IC * HWSZ));
        for (int task = t; task < 1152; task += 512) {   // 128 c-pairs x 9 hw-quads
            int cp = task / 9, hq = task - cp * 9;
            float4 va = x4[(2 * cp) * 9 + hq];
            float4 vb = x4[(2 * cp + 1) * 9 + hq];
            int base = (4 * hq) * 132 + cp;
            unsigned short ha, la, hb, lb;
            bf_split(va.x, ha, la); bf_split(vb.x, hb, lb);
            xsh[base]       = (uint32_t)ha | ((uint32_t)hb << 16);
            xsl[base]       = (uint32_t)la | ((uint32_t)lb << 16);
            bf_split(va.y, ha, la); bf_split(vb.y, hb, lb);
            xsh[base + 132] = (uint32_t)ha | ((uint32_t)hb << 16);
            xsl[base + 132] = (uint32_t)la | ((uint32_t)lb << 16);
            bf_split(va.z, ha, la); bf_split(vb.z, hb, lb);
            xsh[base + 264] = (uint32_t)ha | ((uint32_t)hb << 16);
            xsl[base + 264] = (uint32_t)la | ((uint32_t)lb << 16);
            bf_split(va.w, ha, la); bf_split(vb.w, hb, lb);
            xsh[base + 396] = (uint32_t)ha | ((uint32_t)hb << 16);
            xsl[base + 396] = (uint32_t)la | ((uint32_t)lb << 16);
        }
    }
    __syncthreads();

    // ---- phase 1: GEMM (bf16 3-pass); wave wv does capsule wv, dual waves also kB
    f32x4 acc1[3] = {}, acc2[3] = {};
    #pragma unroll 2
    for (int kt = 0; kt < 8; ++kt) {
        int woff = (wv * 16 + row) * 256 + kt * 32 + g * 8;
        bf16x8 bh1 = *(const bf16x8*)(g_whi + woff);
        bf16x8 bl1 = *(const bf16x8*)(g_wlo + woff);
        bf16x8 bh2 = bh1, bl2 = bl1;
        if (dual) {
            int woff2 = (kB * 16 + row) * 256 + kt * 32 + g * 8;
            bh2 = *(const bf16x8*)(g_whi + woff2);
            bl2 = *(const bf16x8*)(g_wlo + woff2);
        }
        #pragma unroll
        for (int nt = 0; nt < 3; ++nt) {
            int o2 = (nt * 16 + row) * 264 + kt * 32 + g * 8;
            bf16x8 ah = *(const bf16x8*)(xshS + o2);
            bf16x8 al = *(const bf16x8*)(xslS + o2);
            acc1[nt] = mfma16(ah, bh1, acc1[nt]);
            acc1[nt] = mfma16(al, bh1, acc1[nt]);
            acc1[nt] = mfma16(ah, bl1, acc1[nt]);
            if (dual) {
                acc2[nt] = mfma16(ah, bh2, acc2[nt]);
                acc2[nt] = mfma16(al, bh2, acc2[nt]);
                acc2[nt] = mfma16(ah, bl2, acc2[nt]);
            }
        }
    }
    __syncthreads();    // all xs reads done -> caps may overlay xs

    // ---- C-write: caps[k][o*36+hw]; wave writes/reads only its own capsule slices
    {
        float bias1 = conv_b[wv * 16 + row];
        float bias2 = dual ? conv_b[kB * 16 + row] : 0.f;
        #pragma unroll
        for (int nt = 0; nt < 3; ++nt) {
            #pragma unroll
            for (int r = 0; r < 4; ++r) {
                int hw = nt * 16 + g * 4 + r;
                if (hw < HWSZ) {
                    caps_s[wv * 576 + row * HWSZ + hw] = acc1[nt][r] + bias1;
                    if (dual) caps_s[kB * 576 + row * HWSZ + hw] = acc2[nt][r] + bias2;
                }
            }
        }
    }

    // ---- phase 2: u in registers; lane (pr,e) holds u[k][4*p4+pr][e]
    float u1r[18], u2r[18];
    float part1 = 0.f, part2 = 0.f;
    #pragma unroll
    for (int p4 = 0; p4 < 18; ++p4) {
        int p = 4 * p4 + pr;
        {
            const float4* cp4 = (const float4*)(caps_s + wv * 576 + p * 8);
            float4 c0 = cp4[0], c1 = cp4[1];
            const float4* wq = (const float4*)(g_wtsT + ((size_t)(wv * PRIM + p) * 16 + e) * 8);
            float4 w0 = wq[0], w1 = wq[1];
            float a = c0.x * w0.x;
            a = fmaf(c0.y, w0.y, a); a = fmaf(c0.z, w0.z, a); a = fmaf(c0.w, w0.w, a);
            a = fmaf(c1.x, w1.x, a); a = fmaf(c1.y, w1.y, a);
            a = fmaf(c1.z, w1.z, a); a = fmaf(c1.w, w1.w, a);
            u1r[p4] = a; part1 += a;
        }
        if (dual) {
            const float4* cp4 = (const float4*)(caps_s + kB * 576 + p * 8);
            float4 c0 = cp4[0], c1 = cp4[1];
            const float4* wq = (const float4*)(g_wtsT + ((size_t)(kB * PRIM + p) * 16 + e) * 8);
            float4 w0 = wq[0], w1 = wq[1];
            float a = c0.x * w0.x;
            a = fmaf(c0.y, w0.y, a); a = fmaf(c0.z, w0.z, a); a = fmaf(c0.w, w0.w, a);
            a = fmaf(c1.x, w1.x, a); a = fmaf(c1.y, w1.y, a);
            a = fmaf(c1.z, w1.z, a); a = fmaf(c1.w, w1.w, a);
            u2r[p4] = a; part2 += a;
        }
    }

    // ---- routing iter 1: b=0 -> c=0.1 exactly; registers + shuffles, no barrier
    float v1, v2 = 0.f;
    {
        float s1 = part1 + __shfl_xor(part1, 16);
        s1 += __shfl_xor(s1, 32);
        s1 *= 0.1f;
        float q1 = s1 * s1;
        q1 += __shfl_xor(q1, 1); q1 += __shfl_xor(q1, 2);
        q1 += __shfl_xor(q1, 4); q1 += __shfl_xor(q1, 8);
        v1 = s1 * (q1 / (1.f + q1)) * rsqrtf(q1 + 1e-8f);
        if (dual) {
            float s2 = part2 + __shfl_xor(part2, 16);
            s2 += __shfl_xor(s2, 32);
            s2 *= 0.1f;
            float q2 = s2 * s2;
            q2 += __shfl_xor(q2, 1); q2 += __shfl_xor(q2, 2);
            q2 += __shfl_xor(q2, 4); q2 += __shfl_xor(q2, 8);
            v2 = s2 * (q2 / (1.f + q2)) * rsqrtf(q2 + 1e-8f);
        }
        #pragma unroll
        for (int p4 = 0; p4 < 18; ++p4) {
            float d1 = u1r[p4] * v1;
            d1 += __shfl_xor(d1, 1); d1 += __shfl_xor(d1, 2);
            d1 += __shfl_xor(d1, 4); d1 += __shfl_xor(d1, 8);
            if (e == 0) b_s[wv * PRIM + 4 * p4 + pr] = d1;
            if (dual) {
                float d2 = u2r[p4] * v2;
                d2 += __shfl_xor(d2, 1); d2 += __shfl_xor(d2, 2);
                d2 += __shfl_xor(d2, 4); d2 += __shfl_xor(d2, 8);
                if (e == 0) b_s[kB * PRIM + 4 * p4 + pr] = d2;
            }
        }
    }

    // ---- routing iters 2,3
    #pragma unroll
    for (int it = 1; it < 3; ++it) {
        __syncthreads();              // b_s writes visible; prev c_s reads done
        if (t < PRIM) {               // softmax over k per primary
            float bv[KCAPS];
            float m = -1e30f;
            #pragma unroll
            for (int k2 = 0; k2 < KCAPS; ++k2) { bv[k2] = b_s[k2 * PRIM + t]; m = fmaxf(m, bv[k2]); }
            float sum = 0.f;
            #pragma unroll
            for (int k2 = 0; k2 < KCAPS; ++k2) { bv[k2] = __expf(bv[k2] - m); sum += bv[k2]; }
            float inv = 1.f / sum;
            #pragma unroll
            for (int k2 = 0; k2 < KCAPS; ++k2) c_s[k2 * PRIM + t] = bv[k2] * inv;
        }
        __syncthreads();              // c_s visible
        float pa = 0.f, pb = 0.f;
        #pragma unroll
        for (int p4 = 0; p4 < 18; ++p4) {
            int p = 4 * p4 + pr;
            pa = fmaf(c_s[wv * PRIM + p], u1r[p4], pa);
            if (dual) pb = fmaf(c_s[kB * PRIM + p], u2r[p4], pb);
        }
        float s1 = pa + __shfl_xor(pa, 16);
        s1 += __shfl_xor(s1, 32);
        float q1 = s1 * s1;
        q1 += __shfl_xor(q1, 1); q1 += __shfl_xor(q1, 2);
        q1 += __shfl_xor(q1, 4); q1 += __shfl_xor(q1, 8);
        v1 = s1 * (q1 / (1.f + q1)) * rsqrtf(q1 + 1e-8f);
        if (dual) {
            float s2 = pb + __shfl_xor(pb, 16);
            s2 += __shfl_xor(s2, 32);
            float q2 = s2 * s2;
            q2 += __shfl_xor(q2, 1); q2 += __shfl_xor(q2, 2);
            q2 += __shfl_xor(q2, 4); q2 += __shfl_xor(q2, 8);
            v2 = s2 * (q2 / (1.f + q2)) * rsqrtf(q2 + 1e-8f);
        }
        if (it < 2) {                 // agreement update (skip after final iter)
            #pragma unroll
            for (int p4 = 0; p4 < 18; ++p4) {
                float d1 = u1r[p4] * v1;
                d1 += __shfl_xor(d1, 1); d1 += __shfl_xor(d1, 2);
                d1 += __shfl_xor(d1, 4); d1 += __shfl_xor(d1, 8);
                if (e == 0) b_s[wv * PRIM + 4 * p4 + pr] += d1;
                if (dual) {
                    float d2 = u2r[p4] * v2;
                    d2 += __shfl_xor(d2, 1); d2 += __shfl_xor(d2, 2);
                    d2 += __shfl_xor(d2, 4); d2 += __shfl_xor(d2, 8);
                    if (e == 0) b_s[kB * PRIM + 4 * p4 + pr] += d2;
                }
            }
        }
    }

    if (ln < 16) {
        out[(size_t)bb * (KCAPS * EDIM) + wv * 16 + ln] = v1;
        if (dual) out[(size_t)bb * (KCAPS * EDIM) + kB * 16 + ln] = v2;
    }
}

extern "C" void kernel_launch(void* const* d_in, const int* in_sizes, int n_in,
                              void* d_out, int out_size, void* d_ws, size_t ws_size,
                              hipStream_t stream) {
    const float* x  = (const float*)d_in[0];
    const float* cw = (const float*)d_in[1];
    const float* cb = (const float*)d_in[2];
    const float* wt = (const float*)d_in[3];
    float* out = (float*)d_out;
    const int B = in_sizes[0] / (IC * HWSZ);   // 2048

    hipLaunchKernelGGL(prep_kernel, dim3((KCAPS * PRIM * EDIM * PD + 255) / 256), dim3(256),
                       0, stream, cw, wt);

    hipFuncSetAttribute(reinterpret_cast<const void*>(&caps_512),
                        hipFuncAttributeMaxDynamicSharedMemorySize, SMEM_BYTES);
    hipLaunchKernelGGL(caps_512, dim3(B), dim3(512), SMEM_BYTES, stream, x, cb, out);
}